// Round 15
// baseline (99.221 us; speedup 1.0000x reference)
//
#include <hip/hip_runtime.h>
#include <hip/hip_bf16.h>

// out[m, p*64+q] = sum_{k,l} x[m, k*64+l] * A[p,k] * B[q,l] + bias[p*64+q]
// Round 15: block-cooperative, ONE ROW PER BLOCK, 8192 blocks = 4x the
// resident capacity (8 blocks/CU). Oversubscription makes retiring blocks'
// NT-store drains overlap fresh blocks' load bursts -> continuously mixed
// read+write traffic (the regime where the copy ubench hits 6.3 TB/s),
// instead of the device-wide lockstep read/compute/store phases that every
// grid==capacity round (R7..R14) was stuck in.
// Work split: stage 1 is k-parallel -> wave wv loads x rows [16wv,16wv+16)
// (4 KB contiguous), writes its U k-quarter to block-shared U; barrier;
// every wave reads full-U fragments; barrier; wave wv computes output rows
// p in [16wv,16wv+16) (only needs its own 2 A-fragments), stages 4 KB in
// LDS, linear NT stores. Per-element arithmetic identical to R13.

typedef __bf16 bf16x8 __attribute__((ext_vector_type(8)));
typedef __bf16 bf16x4 __attribute__((ext_vector_type(4)));
typedef float  f32x4  __attribute__((ext_vector_type(4)));

#define MFMA16(Aop, Bop, C) __builtin_amdgcn_mfma_f32_16x16x32_bf16(Aop, Bop, C, 0, 0, 0)

__device__ __forceinline__ bf16x8 load_cvt8(const float* __restrict__ p) {
    const float4 a = *reinterpret_cast<const float4*>(p);
    const float4 b = *reinterpret_cast<const float4*>(p + 4);
    bf16x8 r;
    r[0] = (__bf16)a.x; r[1] = (__bf16)a.y; r[2] = (__bf16)a.z; r[3] = (__bf16)a.w;
    r[4] = (__bf16)b.x; r[5] = (__bf16)b.y; r[6] = (__bf16)b.z; r[7] = (__bf16)b.w;
    return r;
}

__global__ __launch_bounds__(256, 4)
void kron_linear_kernel(const float* __restrict__ x,
                        const float* __restrict__ A,
                        const float* __restrict__ B,
                        const float* __restrict__ bias,
                        float* __restrict__ out) {
    // [0,8192): block-shared U (64x64 bf16, k-contiguous, (q&7)<<4 swizzle).
    // [8192,16384): out-staging for waves 0,1 (4 KB each).
    // Waves 2,3 reuse [0,8192) for staging AFTER barrier 2 (U dead by then).
    __shared__ __align__(16) char lds[16384];

    const int lane = threadIdx.x & 63;
    const int wv   = threadIdx.x >> 6;   // 0..3: k-quarter owner / p-quarter owner
    const int lr   = lane & 15;
    const int hi   = lane >> 4;
    const int m    = blockIdx.x;         // row id, 0..8191

    char* Ubase = lds;
    char* sbase = (wv < 2) ? (lds + 8192 + wv * 4096) : (lds + (wv - 2) * 4096);

    const float* xrow = x + (size_t)m * 4096;

    // ---- X fragments (wave's k-quarter): lane holds X[16wv+lr][32kt+8hi+j].
    // Wave reads rows [16wv,16wv+16) = 4 KB contiguous. ----
    bf16x8 Xf[2];
    #pragma unroll
    for (int kt = 0; kt < 2; ++kt) {
        Xf[kt] = load_cvt8(xrow + (16 * wv + lr) * 64 + 32 * kt + 8 * hi);
    }

    // ---- Constant fragments: full B (stage-1), own A quarter (stage-2). ----
    bf16x8 Bf[4][2], Af[2];
    #pragma unroll
    for (int t = 0; t < 4; ++t) {
        #pragma unroll
        for (int kt = 0; kt < 2; ++kt) {
            Bf[t][kt] = load_cvt8(B + (16 * t + lr) * 64 + 32 * kt + 8 * hi);
        }
    }
    #pragma unroll
    for (int kt = 0; kt < 2; ++kt) {
        Af[kt] = load_cvt8(A + (16 * wv + lr) * 64 + 32 * kt + 8 * hi);
    }

    // ---- Stage 1: U(k,q) = sum_l X(k,l)*B(q,l) for k in [16wv,16wv+16).
    // C/D layout: lane's r-th value is U[16wv + 4hi + r][16nt + lr].
    // U byte off = q*128 + k*2, XOR ((q&7)<<4). 8B-aligned bf16x4 writes. ----
    #pragma unroll
    for (int nt = 0; nt < 4; ++nt) {
        f32x4 u = {0.f, 0.f, 0.f, 0.f};
        u = MFMA16(Xf[0], Bf[nt][0], u);
        u = MFMA16(Xf[1], Bf[nt][1], u);
        const int q   = 16 * nt + lr;
        const int k0  = 16 * wv + 4 * hi;
        const int off = (q * 128 + k0 * 2) ^ ((q & 7) << 4);
        bf16x4 v;
        v[0] = (__bf16)u[0];
        v[1] = (__bf16)u[1];
        v[2] = (__bf16)u[2];
        v[3] = (__bf16)u[3];
        *reinterpret_cast<bf16x4*>(Ubase + off) = v;
    }

    __syncthreads();   // all k-quarters of U written

    // ---- Full-U fragments (stage-2 A-operand): lane holds
    // U[32kt+8hi+j][16qt+lr], one 16B ds_read_b128 each, 2-way max. ----
    bf16x8 Uf[2][4];
    #pragma unroll
    for (int kt = 0; kt < 2; ++kt) {
        #pragma unroll
        for (int qt = 0; qt < 4; ++qt) {
            const int q   = 16 * qt + lr;
            const int off = (q * 128 + 64 * kt + 16 * hi) ^ ((q & 7) << 4);
            Uf[kt][qt] = *reinterpret_cast<const bf16x8*>(Ubase + off);
        }
    }

    __syncthreads();   // all Uf reads done -> U region reusable for staging

    // ---- Stage 2 (transposed): wave computes out rows p in [16wv,16wv+16).
    // Lane's r-th acc value is out[p=16wv+lr][q=16qt+4hi+r]. Stage the 16x64
    // f32 quarter-tile (4 KB) in the wave's region, then linear NT stores
    // (one instruction = 64 lanes x 16B = 1 KB contiguous). ----
    float* orow = out + (size_t)m * 4096;
    #pragma unroll
    for (int qt = 0; qt < 4; ++qt) {
        f32x4 acc = {0.f, 0.f, 0.f, 0.f};
        acc = MFMA16(Uf[0][qt], Af[0], acc);
        acc = MFMA16(Uf[1][qt], Af[1], acc);
        const int q0  = 16 * qt + 4 * hi;
        const int off = (lr * 256 + q0 * 4) ^ ((lr & 7) << 4);
        *reinterpret_cast<f32x4*>(sbase + off) = acc;
    }
    asm volatile("s_waitcnt lgkmcnt(0)" ::: "memory");

    // Linear read-back: lane reads row pp = 4i+hi, 16B at col 4*lr;
    // bias added here (off the MFMA chain), then NT store.
    #pragma unroll
    for (int i = 0; i < 4; ++i) {
        const int pp  = 4 * i + hi;
        const int off = (i * 1024 + lane * 16) ^ ((pp & 7) << 4);
        const f32x4 v = *reinterpret_cast<const f32x4*>(sbase + off);
        const int col = 1024 * wv + i * 256 + lane * 4;
        const f32x4 bv = *reinterpret_cast<const f32x4*>(bias + col);
        f32x4 o;
        o[0] = v[0] + bv[0];
        o[1] = v[1] + bv[1];
        o[2] = v[2] + bv[2];
        o[3] = v[3] + bv[3];
        __builtin_nontemporal_store(o, reinterpret_cast<f32x4*>(orow + col));
    }
}

extern "C" void kernel_launch(void* const* d_in, const int* in_sizes, int n_in,
                              void* d_out, int out_size, void* d_ws, size_t ws_size,
                              hipStream_t stream) {
    const float* x    = (const float*)d_in[0];
    const float* A    = (const float*)d_in[1];
    const float* B    = (const float*)d_in[2];
    const float* bias = (const float*)d_in[3];
    float* out        = (float*)d_out;

    // One row per block: 8192 blocks = 4x resident capacity (8 blocks/CU at
    // 16 KB LDS) -> continuous generation turnover mixes load and store
    // phases at the memory system.
    kron_linear_kernel<<<dim3(8192), dim3(256), 0, stream>>>(x, A, B, bias, out);
}

// Round 16
// 97.437 us; speedup vs baseline: 1.0183x; 1.0183x over previous
//
#include <hip/hip_runtime.h>
#include <hip/hip_bf16.h>

// out[m, p*64+q] = sum_{k,l} x[m, k*64+l] * A[p,k] * B[q,l] + bias[p*64+q]
// Per row m: U = X * B^T (contract l), then out_tile^T = U^T * A^T (contract k).
// Round 16: HALF-OUTPUT WAVES, zero barriers. Wave = (row, p-half):
// 16384 waves = 2 residency generations of fully independent waves.
// Each wave runs full stage-1 (U compute duplicated across the pair -- 16
// extra MFMAs/row, free at 4% MfmaUtil) but only its p-half of stage-2
// (half the A fragments, bias, staging and NT stores) -> shorter latency
// lifetime per wave, and generation-1's store drain overlaps generation-2's
// load burst (mixed read+write traffic, the copy-ubench regime). The pair
// sharing a row sits in the same block so the duplicate x-row read hits
// L1/L2, not HBM. Body otherwise identical to R13 (best known, 57.6us):
// 4 KB/wave LDS, k-chunked U, (q&7)<<4 swizzle, bias in epilogue, NT stores.

typedef __bf16 bf16x8 __attribute__((ext_vector_type(8)));
typedef __bf16 bf16x4 __attribute__((ext_vector_type(4)));
typedef float  f32x4  __attribute__((ext_vector_type(4)));

#define MFMA16(Aop, Bop, C) __builtin_amdgcn_mfma_f32_16x16x32_bf16(Aop, Bop, C, 0, 0, 0)

__device__ __forceinline__ bf16x8 load_cvt8(const float* __restrict__ p) {
    const float4 a = *reinterpret_cast<const float4*>(p);
    const float4 b = *reinterpret_cast<const float4*>(p + 4);
    bf16x8 r;
    r[0] = (__bf16)a.x; r[1] = (__bf16)a.y; r[2] = (__bf16)a.z; r[3] = (__bf16)a.w;
    r[4] = (__bf16)b.x; r[5] = (__bf16)b.y; r[6] = (__bf16)b.z; r[7] = (__bf16)b.w;
    return r;
}

__global__ __launch_bounds__(256, 4)
void kron_linear_kernel(const float* __restrict__ x,
                        const float* __restrict__ A,
                        const float* __restrict__ B,
                        const float* __restrict__ bias,
                        float* __restrict__ out) {
    // ONE 4 KB buffer per wave, reused in sequence:
    //  (a) U chunk 0: U[k][q], k in [0,32)   (bf16, k-contiguous, swizzled)
    //  (b) U chunk 1: U[k][q], k in [32,64)
    //  (c) 16x64 f32 output quarter-tiles (2 of them for this wave's p-half)
    __shared__ __align__(16) char Ulds[4][4096];

    const int lane = threadIdx.x & 63;
    const int wv   = threadIdx.x >> 6;            // wave in block, 0..3
    const int lr   = lane & 15;                   // lane % 16
    const int hi   = lane >> 4;                   // 0..3
    const int m    = blockIdx.x * 2 + (wv >> 1);  // row id, 0..8191
    const int hh   = wv & 1;                      // p-half: p in [32*hh, 32*hh+32)

    char* ubase = &Ulds[wv][0];
    const float* xrow = x + (size_t)m * 4096;

    // ---- Constant fragments ----
    // Af[ptl][kt]: lane holds A[16*(2hh+ptl)+lr][32kt + 8hi + j] (own p-half)
    // Bf[t][kt]:   lane holds B[16t+lr][32kt + 8hi + j]          (full B)
    bf16x8 Af[2][2], Bf[4][2];
    #pragma unroll
    for (int t = 0; t < 4; ++t) {
        #pragma unroll
        for (int kt = 0; kt < 2; ++kt) {
            Bf[t][kt] = load_cvt8(B + (16 * t + lr) * 64 + 32 * kt + 8 * hi);
        }
    }
    #pragma unroll
    for (int ptl = 0; ptl < 2; ++ptl) {
        #pragma unroll
        for (int kt = 0; kt < 2; ++kt) {
            const int row = 16 * (2 * hh + ptl) + lr;
            Af[ptl][kt] = load_cvt8(A + row * 64 + 32 * kt + 8 * hi);
        }
    }

    // ---- X fragments: full row (stage-1 needs all k). lane holds
    // X[16mt+lr][32kt+8hi+j]. Pair-wave reads the same row -> L1/L2 hit. ----
    bf16x8 Xf[4][2];
    #pragma unroll
    for (int mt = 0; mt < 4; ++mt) {
        #pragma unroll
        for (int kt = 0; kt < 2; ++kt) {
            Xf[mt][kt] = load_cvt8(xrow + (16 * mt + lr) * 64 + 32 * kt + 8 * hi);
        }
    }

    // ---- Stage 1 + U transpose, k-chunked through the 4 KB buffer.
    // Chunk c holds U[k][q], k in [32c, 32c+32). Byte off (local k'):
    // off = q*64 + k'*2, XOR-swizzled by ((q&7)<<4)  [2-way max, free].
    // Write side: lane's r-th C/D value is U[16mt + 4hi + r][16nt + lr].
    // Read side (Uf[c][qt]): lane reads U[32c + 8hi + j][16qt + lr], j=0..7,
    // one ds_read_b128 at off = q*64 + 16*hi (16B-aligned, swizzle-safe). ----
    bf16x8 Uf[2][4];
    #pragma unroll
    for (int c = 0; c < 2; ++c) {
        if (c == 1) {
            // Chunk-0 fragment reads must complete before overwrite.
            asm volatile("s_waitcnt lgkmcnt(0)" ::: "memory");
        }
        #pragma unroll
        for (int mtl = 0; mtl < 2; ++mtl) {
            const int mt = 2 * c + mtl;
            #pragma unroll
            for (int nt = 0; nt < 4; ++nt) {
                f32x4 u = {0.f, 0.f, 0.f, 0.f};
                u = MFMA16(Xf[mt][0], Bf[nt][0], u);
                u = MFMA16(Xf[mt][1], Bf[nt][1], u);
                const int q   = 16 * nt + lr;
                const int kl  = 16 * mtl + 4 * hi;   // k within chunk
                const int off = (q * 64 + kl * 2) ^ ((q & 7) << 4);
                bf16x4 v;
                v[0] = (__bf16)u[0];
                v[1] = (__bf16)u[1];
                v[2] = (__bf16)u[2];
                v[3] = (__bf16)u[3];
                *reinterpret_cast<bf16x4*>(ubase + off) = v;
            }
        }
        asm volatile("s_waitcnt lgkmcnt(0)" ::: "memory");
        #pragma unroll
        for (int qt = 0; qt < 4; ++qt) {
            const int q   = 16 * qt + lr;
            const int off = (q * 64 + 16 * hi) ^ ((q & 7) << 4);
            Uf[c][qt] = *reinterpret_cast<const bf16x8*>(ubase + off);
        }
    }
    // Chunk-1 fragment data must be in registers before out-staging reuses
    // the buffer.
    asm volatile("s_waitcnt lgkmcnt(0)" ::: "memory");

    // ---- Stage 2 (transposed), OWN P-HALF ONLY: D[q][p] = sum_k U^T A^T.
    // Quarter h = 2hh + hq, p = 16h + lr. Lane's r-th acc value is
    // out[p][q=16qt+4hi+r]. Stage each 16x64 f32 quarter-tile (4 KB) in
    // LDS, then stream it out linearly (1 KB contiguous per instruction). ----
    float* orow = out + (size_t)m * 4096;
    #pragma unroll
    for (int hq = 0; hq < 2; ++hq) {
        const int h = 2 * hh + hq;
        #pragma unroll
        for (int qt = 0; qt < 4; ++qt) {
            f32x4 acc = {0.f, 0.f, 0.f, 0.f};
            acc = MFMA16(Uf[0][qt], Af[hq][0], acc);
            acc = MFMA16(Uf[1][qt], Af[hq][1], acc);
            const int pp  = lr;                  // row within quarter-tile
            const int q0  = 16 * qt + 4 * hi;
            const int off = (pp * 256 + q0 * 4) ^ ((pp & 7) << 4);
            *reinterpret_cast<f32x4*>(ubase + off) = acc;
        }
        asm volatile("s_waitcnt lgkmcnt(0)" ::: "memory");

        // Linear read-back: lane reads row pp = 4i+hi, 16B at col 4*lane;
        // bias added here (off the MFMA chain), then NT store.
        #pragma unroll
        for (int i = 0; i < 4; ++i) {
            const int pp  = 4 * i + hi;
            const int off = (i * 1024 + lane * 16) ^ ((pp & 7) << 4);
            const f32x4 v = *reinterpret_cast<const f32x4*>(ubase + off);
            const int col = 1024 * h + i * 256 + lane * 4;
            const f32x4 bv = *reinterpret_cast<const f32x4*>(bias + col);
            f32x4 o;
            o[0] = v[0] + bv[0];
            o[1] = v[1] + bv[1];
            o[2] = v[2] + bv[2];
            o[3] = v[3] + bv[3];
            __builtin_nontemporal_store(o, reinterpret_cast<f32x4*>(orow + col));
        }
        // Quarter-tile reads must complete before the next quarter overwrites.
        asm volatile("s_waitcnt lgkmcnt(0)" ::: "memory");
    }
}

extern "C" void kernel_launch(void* const* d_in, const int* in_sizes, int n_in,
                              void* d_out, int out_size, void* d_ws, size_t ws_size,
                              hipStream_t stream) {
    const float* x    = (const float*)d_in[0];
    const float* A    = (const float*)d_in[1];
    const float* B    = (const float*)d_in[2];
    const float* bias = (const float*)d_in[3];
    float* out        = (float*)d_out;

    // 4096 blocks x 4 waves = 16384 half-row waves = 2 barrier-free
    // residency generations: gen-1 store drains overlap gen-2 load bursts.
    kron_linear_kernel<<<dim3(4096), dim3(256), 0, stream>>>(x, A, B, bias, out);
}

// Round 17
// 57.750 us; speedup vs baseline: 1.7181x; 1.6872x over previous
//
#include <hip/hip_runtime.h>
#include <hip/hip_bf16.h>

// out[m, p*64+q] = sum_{k,l} x[m, k*64+l] * A[p,k] * B[q,l] + bias[p*64+q]
// Per row m: U = X * B^T (contract l), then out_tile^T = U^T * A^T (contract k).
// One wave per row, 8192 waves. MFMA 16x16x32 bf16, fp32 accumulate.
// FINAL (= Round 13, best measured: 57.6 us wall, 197 MB HBM traffic):
//  - one independent wave per output row; zero barriers; 4-wave 256-thread
//    blocks; 2048 blocks = full single-generation residency (8 blocks/CU,
//    VGPR 64, 16 KB LDS/block). Nine structural probes (register pipeline,
//    block-cooperative split, oversubscription, half-row waves, smaller
//    blocks, bigger LDS, write-back stores) all regressed 10-70%.
//  - 4 KB/wave LDS reused (a) U chunk 0, (b) U chunk 1, (c) f32 out-staging.
//  - (q&7)<<4 XOR swizzle: all LDS ops <=2-way conflicts.
//  - bias added in the epilogue (off the MFMA chain; C-init coupling L2
//    latency into MFMA cost +9% in R12).
//  - NT f32x4 stores from LDS-staged tiles: 1 KB contiguous per instruction
//    (write amplification 1.39x -> 1.0, R7); NT beats write-back (R14).

typedef __bf16 bf16x8 __attribute__((ext_vector_type(8)));
typedef __bf16 bf16x4 __attribute__((ext_vector_type(4)));
typedef float  f32x4  __attribute__((ext_vector_type(4)));

#define MFMA16(Aop, Bop, C) __builtin_amdgcn_mfma_f32_16x16x32_bf16(Aop, Bop, C, 0, 0, 0)

__device__ __forceinline__ bf16x8 load_cvt8(const float* __restrict__ p) {
    const float4 a = *reinterpret_cast<const float4*>(p);
    const float4 b = *reinterpret_cast<const float4*>(p + 4);
    bf16x8 r;
    r[0] = (__bf16)a.x; r[1] = (__bf16)a.y; r[2] = (__bf16)a.z; r[3] = (__bf16)a.w;
    r[4] = (__bf16)b.x; r[5] = (__bf16)b.y; r[6] = (__bf16)b.z; r[7] = (__bf16)b.w;
    return r;
}

__global__ __launch_bounds__(256, 4)
void kron_linear_kernel(const float* __restrict__ x,
                        const float* __restrict__ A,
                        const float* __restrict__ B,
                        const float* __restrict__ bias,
                        float* __restrict__ out) {
    // ONE 4 KB buffer per wave, reused in sequence:
    //  (a) U chunk 0: U[k][q], k in [0,32)   (bf16, k-contiguous, swizzled)
    //  (b) U chunk 1: U[k][q], k in [32,64)
    //  (c) 16x64 f32 output quarter-tiles (4 of them)
    __shared__ __align__(16) char Ulds[4][4096];

    const int lane = threadIdx.x & 63;
    const int wv   = threadIdx.x >> 6;    // wave in block, 0..3
    const int lr   = lane & 15;           // lane % 16
    const int hi   = lane >> 4;           // 0..3
    const int m    = blockIdx.x * 4 + wv; // row id, 0..8191

    char* ubase = &Ulds[wv][0];
    const float* xrow = x + (size_t)m * 4096;

    // ---- Constant fragments ----
    // Af[t][kt]: lane holds A[16t+lr][32kt + 8hi + j]   (stage-2 B-operand = A^T)
    // Bf[t][kt]: lane holds B[16t+lr][32kt + 8hi + j]   (stage-1 B-operand)
    bf16x8 Af[4][2], Bf[4][2];
    #pragma unroll
    for (int t = 0; t < 4; ++t) {
        #pragma unroll
        for (int kt = 0; kt < 2; ++kt) {
            const int row = 16 * t + lr;
            const int c0  = 32 * kt + 8 * hi;
            Af[t][kt] = load_cvt8(A + row * 64 + c0);
            Bf[t][kt] = load_cvt8(B + row * 64 + c0);
        }
    }

    // ---- X fragments: stage-1 A-operand. lane holds X[16mt+lr][32kt+8hi+j] ----
    bf16x8 Xf[4][2];
    #pragma unroll
    for (int mt = 0; mt < 4; ++mt) {
        #pragma unroll
        for (int kt = 0; kt < 2; ++kt) {
            Xf[mt][kt] = load_cvt8(xrow + (16 * mt + lr) * 64 + 32 * kt + 8 * hi);
        }
    }

    // ---- Stage 1 + U transpose, k-chunked through the 4 KB buffer.
    // Chunk c holds U[k][q], k in [32c, 32c+32). Byte off (local k'):
    // off = q*64 + k'*2, XOR-swizzled by ((q&7)<<4)  [2-way max, free].
    // Write side: lane's r-th C/D value is U[16mt + 4hi + r][16nt + lr].
    // Read side (Uf[c][qt]): lane reads U[32c + 8hi + j][16qt + lr], j=0..7,
    // one ds_read_b128 at off = q*64 + 16*hi (16B-aligned, swizzle-safe). ----
    bf16x8 Uf[2][4];
    #pragma unroll
    for (int c = 0; c < 2; ++c) {
        if (c == 1) {
            // Chunk-0 fragment reads must complete before overwrite.
            asm volatile("s_waitcnt lgkmcnt(0)" ::: "memory");
        }
        #pragma unroll
        for (int mtl = 0; mtl < 2; ++mtl) {
            const int mt = 2 * c + mtl;
            #pragma unroll
            for (int nt = 0; nt < 4; ++nt) {
                f32x4 u = {0.f, 0.f, 0.f, 0.f};
                u = MFMA16(Xf[mt][0], Bf[nt][0], u);
                u = MFMA16(Xf[mt][1], Bf[nt][1], u);
                const int q   = 16 * nt + lr;
                const int kl  = 16 * mtl + 4 * hi;   // k within chunk
                const int off = (q * 64 + kl * 2) ^ ((q & 7) << 4);
                bf16x4 v;
                v[0] = (__bf16)u[0];
                v[1] = (__bf16)u[1];
                v[2] = (__bf16)u[2];
                v[3] = (__bf16)u[3];
                *reinterpret_cast<bf16x4*>(ubase + off) = v;
            }
        }
        asm volatile("s_waitcnt lgkmcnt(0)" ::: "memory");
        #pragma unroll
        for (int qt = 0; qt < 4; ++qt) {
            const int q   = 16 * qt + lr;
            const int off = (q * 64 + 16 * hi) ^ ((q & 7) << 4);
            Uf[c][qt] = *reinterpret_cast<const bf16x8*>(ubase + off);
        }
    }
    // Chunk-1 fragment data must be in registers before out-staging reuses
    // the buffer.
    asm volatile("s_waitcnt lgkmcnt(0)" ::: "memory");

    // ---- Stage 2 (transposed): D[q][p] = sum_k U^T[q][k] * A^T[k][p].
    // Lane's r-th acc value is out[p=16h+lr][q=16qt+4hi+r]. Stage each
    // 16-row quarter-tile (4 KB f32) in LDS, then stream it out linearly:
    // one instruction = 64 lanes x 16B = 1 KB contiguous.
    // Staging off = pp*256 + q0*4, swizzled by ((pp&7)<<4), pp = row in tile. ----
    float* orow = out + (size_t)m * 4096;
    #pragma unroll
    for (int h = 0; h < 4; ++h) {
        #pragma unroll
        for (int qt = 0; qt < 4; ++qt) {
            f32x4 acc = {0.f, 0.f, 0.f, 0.f};
            acc = MFMA16(Uf[0][qt], Af[h][0], acc);
            acc = MFMA16(Uf[1][qt], Af[h][1], acc);
            const int pp  = lr;                  // row within quarter-tile
            const int q0  = 16 * qt + 4 * hi;
            const int off = (pp * 256 + q0 * 4) ^ ((pp & 7) << 4);
            *reinterpret_cast<f32x4*>(ubase + off) = acc;
        }
        asm volatile("s_waitcnt lgkmcnt(0)" ::: "memory");

        // Linear read-back: lane reads row pp = 4i+hi, 16B at col 4*lane;
        // bias added here (off the MFMA chain), then NT store.
        #pragma unroll
        for (int i = 0; i < 4; ++i) {
            const int pp  = 4 * i + hi;
            const int off = (i * 1024 + lane * 16) ^ ((pp & 7) << 4);
            const f32x4 v = *reinterpret_cast<const f32x4*>(ubase + off);
            const int col = 1024 * h + i * 256 + lane * 4;
            const f32x4 bv = *reinterpret_cast<const f32x4*>(bias + col);
            f32x4 o;
            o[0] = v[0] + bv[0];
            o[1] = v[1] + bv[1];
            o[2] = v[2] + bv[2];
            o[3] = v[3] + bv[3];
            __builtin_nontemporal_store(o, reinterpret_cast<f32x4*>(orow + col));
        }
        // Quarter-tile reads must complete before the next quarter overwrites.
        asm volatile("s_waitcnt lgkmcnt(0)" ::: "memory");
    }
}

extern "C" void kernel_launch(void* const* d_in, const int* in_sizes, int n_in,
                              void* d_out, int out_size, void* d_ws, size_t ws_size,
                              hipStream_t stream) {
    const float* x    = (const float*)d_in[0];
    const float* A    = (const float*)d_in[1];
    const float* B    = (const float*)d_in[2];
    const float* bias = (const float*)d_in[3];
    float* out        = (float*)d_out;

    // 2048 blocks x 4 waves = 8192 waves, one output row each.
    // 16 KB LDS/block + VGPR 64 -> 8 blocks/CU = full-residency geometry.
    kron_linear_kernel<<<dim3(2048), dim3(256), 0, stream>>>(x, A, B, bias, out);
}